// Round 1
// baseline (346.461 us; speedup 1.0000x reference)
//
#include <hip/hip_runtime.h>
#include <hip/hip_bf16.h>

// PQ sim: sim = decode(x) @ decode(tgt)^T via bf16x2-split GEMM.
// n=4096 queries, m=16384 targets, M=64 subspaces, ksub=256, dsub=8, D=512.

#define D_FULL 512
#define M_SUB 64
#define KSUB 256
#define DSUB 8
#define KP 1536  // augmented K: [hi|lo|hi] x [hi|hi|lo]

typedef short bf16x8 __attribute__((ext_vector_type(8)));
typedef float f32x4 __attribute__((ext_vector_type(4)));

static __device__ __forceinline__ unsigned short f2bf(float f) {
  __hip_bfloat16 h = __float2bfloat16(f);
  unsigned short u;
  __builtin_memcpy(&u, &h, 2);
  return u;
}
static __device__ __forceinline__ float bf2f(unsigned short u) {
  unsigned int v = ((unsigned int)u) << 16;
  float f;
  __builtin_memcpy(&f, &v, 4);
  return f;
}

// ---------------- encode + decode queries into A' ----------------
// grid: (64 subspaces, n/256), block 256. Each thread: one (query, subspace).
__global__ void encode_kernel(const float* __restrict__ x,
                              const float* __restrict__ cen,
                              unsigned short* __restrict__ Ap) {
  __shared__ float cs[KSUB][DSUB];
  __shared__ float n2[KSUB];
  const int t = threadIdx.x;
  const int s = blockIdx.x;
  const int i = blockIdx.y * 256 + t;

  const float* cp = cen + ((size_t)s * KSUB + t) * DSUB;
  float4 c0 = *(const float4*)cp;
  float4 c1 = *(const float4*)(cp + 4);
  *(float4*)&cs[t][0] = c0;
  *(float4*)&cs[t][4] = c1;
  n2[t] = c0.x * c0.x + c0.y * c0.y + c0.z * c0.z + c0.w * c0.w +
          c1.x * c1.x + c1.y * c1.y + c1.z * c1.z + c1.w * c1.w;
  __syncthreads();

  float xq[8];
  const float* xp = x + (size_t)i * D_FULL + s * DSUB;
  *(float4*)&xq[0] = *(const float4*)xp;
  *(float4*)&xq[4] = *(const float4*)(xp + 4);

  float best = 1e30f;
  int bk = 0;
  for (int k = 0; k < KSUB; ++k) {
    float dot = 0.f;
#pragma unroll
    for (int d = 0; d < 8; ++d) dot += cs[k][d] * xq[d];
    float dis = n2[k] - 2.0f * dot;
    if (dis < best) { best = dis; bk = k; }  // strict < keeps first index (numpy argmin)
  }

  // decode nearest centroid, split hi/lo bf16, write A' = [Ahi | Alo | Ahi]
  unsigned int hi[4], lo[4];
#pragma unroll
  for (int d = 0; d < 4; ++d) {
    float f0 = cs[bk][2 * d], f1 = cs[bk][2 * d + 1];
    unsigned short h0 = f2bf(f0), h1 = f2bf(f1);
    unsigned short l0 = f2bf(f0 - bf2f(h0)), l1 = f2bf(f1 - bf2f(h1));
    hi[d] = (unsigned int)h0 | ((unsigned int)h1 << 16);
    lo[d] = (unsigned int)l0 | ((unsigned int)l1 << 16);
  }
  uint4 hv, lv;
  hv.x = hi[0]; hv.y = hi[1]; hv.z = hi[2]; hv.w = hi[3];
  lv.x = lo[0]; lv.y = lo[1]; lv.z = lo[2]; lv.w = lo[3];
  size_t base = (size_t)i * KP + s * DSUB;
  *(uint4*)(Ap + base) = hv;            // hi
  *(uint4*)(Ap + base + D_FULL) = lv;   // lo
  *(uint4*)(Ap + base + 2 * D_FULL) = hv;  // hi
}

// ---------------- decode targets into B' ----------------
// one thread per (j, s); wave handles one j (64 subspaces) -> coalesced writes.
__global__ void decode_tgt(const int* __restrict__ tgt,
                           const float* __restrict__ cen,
                           unsigned short* __restrict__ Bp) {
  int g = blockIdx.x * 256 + threadIdx.x;
  int j = g >> 6, s = g & 63;
  int k = tgt[g];
  const float* c = cen + ((size_t)s * KSUB + k) * DSUB;
  float4 v0 = *(const float4*)c;
  float4 v1 = *(const float4*)(c + 4);
  float f[8] = {v0.x, v0.y, v0.z, v0.w, v1.x, v1.y, v1.z, v1.w};
  unsigned int hi[4], lo[4];
#pragma unroll
  for (int d = 0; d < 4; ++d) {
    float f0 = f[2 * d], f1 = f[2 * d + 1];
    unsigned short h0 = f2bf(f0), h1 = f2bf(f1);
    unsigned short l0 = f2bf(f0 - bf2f(h0)), l1 = f2bf(f1 - bf2f(h1));
    hi[d] = (unsigned int)h0 | ((unsigned int)h1 << 16);
    lo[d] = (unsigned int)l0 | ((unsigned int)l1 << 16);
  }
  uint4 hv, lv;
  hv.x = hi[0]; hv.y = hi[1]; hv.z = hi[2]; hv.w = hi[3];
  lv.x = lo[0]; lv.y = lo[1]; lv.z = lo[2]; lv.w = lo[3];
  size_t base = (size_t)j * KP + s * DSUB;
  *(uint4*)(Bp + base) = hv;               // hi
  *(uint4*)(Bp + base + D_FULL) = hv;      // hi
  *(uint4*)(Bp + base + 2 * D_FULL) = lv;  // lo
}

// ---------------- GEMM: C[n,m] = A'[n,KP] * B'[m,KP]^T ----------------
// m97 structure: 128x128 tile, BK=64, 4 waves (2x2), global_load_lds w=16.
__global__ __launch_bounds__(256) void gemm_nt(
    const unsigned short* __restrict__ A, const unsigned short* __restrict__ B,
    float* __restrict__ C, int Mq, int Nt) {
  __shared__ unsigned short As[128 * 64];
  __shared__ unsigned short Bs[128 * 64];
  const int t = threadIdx.x;
  const int lane = t & 63;
  const int w = t >> 6;
  const int wr = w >> 1, wc = w & 1;
  const int bm = blockIdx.y, bn = blockIdx.x;

  const unsigned short* Ab = A + (size_t)bm * 128 * KP;
  const unsigned short* Bb = B + (size_t)bn * 128 * KP;
  const int arow = t >> 3;        // 0..31
  const int acol = (t & 7) * 8;   // bf16 col, 16B chunks

  f32x4 acc[4][4] = {};

  for (int k0 = 0; k0 < KP; k0 += 64) {
#pragma unroll
    for (int it = 0; it < 4; ++it) {
      int r = arow + it * 32;
      __builtin_amdgcn_global_load_lds(
          (const __attribute__((address_space(1))) void*)(Ab + (size_t)r * KP + k0 + acol),
          (__attribute__((address_space(3))) void*)(As + r * 64 + acol), 16, 0, 0);
    }
#pragma unroll
    for (int it = 0; it < 4; ++it) {
      int r = arow + it * 32;
      __builtin_amdgcn_global_load_lds(
          (const __attribute__((address_space(1))) void*)(Bb + (size_t)r * KP + k0 + acol),
          (__attribute__((address_space(3))) void*)(Bs + r * 64 + acol), 16, 0, 0);
    }
    __syncthreads();
#pragma unroll
    for (int kk = 0; kk < 2; ++kk) {
      const int krd = kk * 32 + (lane >> 4) * 8;
      bf16x8 a[4], b[4];
#pragma unroll
      for (int i2 = 0; i2 < 4; ++i2)
        a[i2] = *(const bf16x8*)&As[(wr * 64 + i2 * 16 + (lane & 15)) * 64 + krd];
#pragma unroll
      for (int j2 = 0; j2 < 4; ++j2)
        b[j2] = *(const bf16x8*)&Bs[(wc * 64 + j2 * 16 + (lane & 15)) * 64 + krd];
#pragma unroll
      for (int i2 = 0; i2 < 4; ++i2)
#pragma unroll
        for (int j2 = 0; j2 < 4; ++j2)
          acc[i2][j2] = __builtin_amdgcn_mfma_f32_16x16x32_bf16(a[i2], b[j2], acc[i2][j2], 0, 0, 0);
    }
    __syncthreads();
  }

  const int rb = bm * 128 + wr * 64 + (lane >> 4) * 4;
  const int cb = bn * 128 + wc * 64 + (lane & 15);
#pragma unroll
  for (int i2 = 0; i2 < 4; ++i2)
#pragma unroll
    for (int j2 = 0; j2 < 4; ++j2)
#pragma unroll
      for (int r = 0; r < 4; ++r)
        C[(size_t)(rb + i2 * 16 + r) * Nt + cb + j2 * 16] = acc[i2][j2][r];
}

extern "C" void kernel_launch(void* const* d_in, const int* in_sizes, int n_in,
                              void* d_out, int out_size, void* d_ws, size_t ws_size,
                              hipStream_t stream) {
  const float* x = (const float*)d_in[0];       // [n, 512]
  const float* cen = (const float*)d_in[1];     // [64, 256, 8]
  const int* tgt = (const int*)d_in[2];         // [m, 64]
  float* out = (float*)d_out;                   // [n, m]
  const int n = in_sizes[0] / D_FULL;           // 4096
  const int m = in_sizes[2] / M_SUB;            // 16384

  unsigned short* Ap = (unsigned short*)d_ws;          // [n, 1536] bf16
  unsigned short* Bp = Ap + (size_t)n * KP;            // [m, 1536] bf16

  encode_kernel<<<dim3(M_SUB, n / 256), 256, 0, stream>>>(x, cen, Ap);
  decode_tgt<<<dim3((m * M_SUB) / 256), 256, 0, stream>>>(tgt, cen, Bp);
  gemm_nt<<<dim3(m / 128, n / 128), 256, 0, stream>>>(Ap, Bp, out, n, m);
}

// Round 2
// 161.440 us; speedup vs baseline: 2.1461x; 2.1461x over previous
//
#include <hip/hip_runtime.h>
#include <hip/hip_bf16.h>
#include <hip/hip_fp16.h>

// PQ sim: sim = decode(x) @ decode(tgt)^T via f16 GEMM (K=512).
// n=4096 queries, m=16384 targets, M=64 subspaces, ksub=256, dsub=8, D=512.

#define D_FULL 512
#define M_SUB 64
#define KSUB 256
#define DSUB 8
#define KP 512  // f16 direct, no split

typedef _Float16 f16x8 __attribute__((ext_vector_type(8)));
typedef float f32x4 __attribute__((ext_vector_type(4)));

static __device__ __forceinline__ unsigned int pack2h(float f0, float f1) {
  _Float16 h0 = (_Float16)f0, h1 = (_Float16)f1;
  unsigned short u0, u1;
  __builtin_memcpy(&u0, &h0, 2);
  __builtin_memcpy(&u1, &h1, 2);
  return (unsigned int)u0 | ((unsigned int)u1 << 16);
}

// ---------------- encode + decode queries into A' (f16) ----------------
// grid: (64 subspaces, n/256), block 256. Each thread: one (query, subspace).
__global__ void encode_kernel(const float* __restrict__ x,
                              const float* __restrict__ cen,
                              unsigned short* __restrict__ Ap) {
  __shared__ float cs[KSUB][DSUB];
  __shared__ float n2[KSUB];
  const int t = threadIdx.x;
  const int s = blockIdx.x;
  const int i = blockIdx.y * 256 + t;

  const float* cp = cen + ((size_t)s * KSUB + t) * DSUB;
  float4 c0 = *(const float4*)cp;
  float4 c1 = *(const float4*)(cp + 4);
  *(float4*)&cs[t][0] = c0;
  *(float4*)&cs[t][4] = c1;
  n2[t] = c0.x * c0.x + c0.y * c0.y + c0.z * c0.z + c0.w * c0.w +
          c1.x * c1.x + c1.y * c1.y + c1.z * c1.z + c1.w * c1.w;
  __syncthreads();

  float xq[8];
  const float* xp = x + (size_t)i * D_FULL + s * DSUB;
  *(float4*)&xq[0] = *(const float4*)xp;
  *(float4*)&xq[4] = *(const float4*)(xp + 4);

  float best = 1e30f;
  int bk = 0;
  for (int k = 0; k < KSUB; ++k) {
    float dot = 0.f;
#pragma unroll
    for (int d = 0; d < 8; ++d) dot += cs[k][d] * xq[d];
    float dis = n2[k] - 2.0f * dot;
    if (dis < best) { best = dis; bk = k; }  // strict < keeps first index (numpy argmin)
  }

  uint4 hv;
  hv.x = pack2h(cs[bk][0], cs[bk][1]);
  hv.y = pack2h(cs[bk][2], cs[bk][3]);
  hv.z = pack2h(cs[bk][4], cs[bk][5]);
  hv.w = pack2h(cs[bk][6], cs[bk][7]);
  *(uint4*)(Ap + (size_t)i * KP + s * DSUB) = hv;
}

// ---------------- decode targets into B' (f16) ----------------
// one thread per (j, s); wave handles one j (64 subspaces) -> coalesced 1KB/wave.
__global__ void decode_tgt(const int* __restrict__ tgt,
                           const float* __restrict__ cen,
                           unsigned short* __restrict__ Bp) {
  int g = blockIdx.x * 256 + threadIdx.x;
  int j = g >> 6, s = g & 63;
  int k = tgt[g];
  const float* c = cen + ((size_t)s * KSUB + k) * DSUB;
  float4 v0 = *(const float4*)c;
  float4 v1 = *(const float4*)(c + 4);
  uint4 hv;
  hv.x = pack2h(v0.x, v0.y);
  hv.y = pack2h(v0.z, v0.w);
  hv.z = pack2h(v1.x, v1.y);
  hv.w = pack2h(v1.z, v1.w);
  *(uint4*)(Bp + (size_t)j * KP + s * DSUB) = hv;
}

// ---------------- GEMM: C[n,m] = A'[n,KP] * B'[m,KP]^T ----------------
// m97 structure: 128x128 tile, BK=64, 4 waves (2x2), global_load_lds w=16.
__global__ __launch_bounds__(256) void gemm_nt(
    const unsigned short* __restrict__ A, const unsigned short* __restrict__ B,
    float* __restrict__ C, int Mq, int Nt) {
  __shared__ unsigned short As[128 * 64];
  __shared__ unsigned short Bs[128 * 64];
  const int t = threadIdx.x;
  const int lane = t & 63;
  const int w = t >> 6;
  const int wr = w >> 1, wc = w & 1;
  const int bm = blockIdx.y, bn = blockIdx.x;

  const unsigned short* Ab = A + (size_t)bm * 128 * KP;
  const unsigned short* Bb = B + (size_t)bn * 128 * KP;
  const int arow = t >> 3;        // 0..31
  const int acol = (t & 7) * 8;   // f16 col, 16B chunks

  f32x4 acc[4][4] = {};

  for (int k0 = 0; k0 < KP; k0 += 64) {
#pragma unroll
    for (int it = 0; it < 4; ++it) {
      int r = arow + it * 32;
      __builtin_amdgcn_global_load_lds(
          (const __attribute__((address_space(1))) void*)(Ab + (size_t)r * KP + k0 + acol),
          (__attribute__((address_space(3))) void*)(As + r * 64 + acol), 16, 0, 0);
    }
#pragma unroll
    for (int it = 0; it < 4; ++it) {
      int r = arow + it * 32;
      __builtin_amdgcn_global_load_lds(
          (const __attribute__((address_space(1))) void*)(Bb + (size_t)r * KP + k0 + acol),
          (__attribute__((address_space(3))) void*)(Bs + r * 64 + acol), 16, 0, 0);
    }
    __syncthreads();
#pragma unroll
    for (int kk = 0; kk < 2; ++kk) {
      const int krd = kk * 32 + (lane >> 4) * 8;
      f16x8 a[4], b[4];
#pragma unroll
      for (int i2 = 0; i2 < 4; ++i2)
        a[i2] = *(const f16x8*)&As[(wr * 64 + i2 * 16 + (lane & 15)) * 64 + krd];
#pragma unroll
      for (int j2 = 0; j2 < 4; ++j2)
        b[j2] = *(const f16x8*)&Bs[(wc * 64 + j2 * 16 + (lane & 15)) * 64 + krd];
#pragma unroll
      for (int i2 = 0; i2 < 4; ++i2)
#pragma unroll
        for (int j2 = 0; j2 < 4; ++j2)
          acc[i2][j2] = __builtin_amdgcn_mfma_f32_16x16x32_f16(a[i2], b[j2], acc[i2][j2], 0, 0, 0);
    }
    __syncthreads();
  }

  const int rb = bm * 128 + wr * 64 + (lane >> 4) * 4;
  const int cb = bn * 128 + wc * 64 + (lane & 15);
#pragma unroll
  for (int i2 = 0; i2 < 4; ++i2)
#pragma unroll
    for (int j2 = 0; j2 < 4; ++j2)
#pragma unroll
      for (int r = 0; r < 4; ++r)
        C[(size_t)(rb + i2 * 16 + r) * Nt + cb + j2 * 16] = acc[i2][j2][r];
}

extern "C" void kernel_launch(void* const* d_in, const int* in_sizes, int n_in,
                              void* d_out, int out_size, void* d_ws, size_t ws_size,
                              hipStream_t stream) {
  const float* x = (const float*)d_in[0];       // [n, 512]
  const float* cen = (const float*)d_in[1];     // [64, 256, 8]
  const int* tgt = (const int*)d_in[2];         // [m, 64]
  float* out = (float*)d_out;                   // [n, m]
  const int n = in_sizes[0] / D_FULL;           // 4096
  const int m = in_sizes[2] / M_SUB;            // 16384

  unsigned short* Ap = (unsigned short*)d_ws;          // [n, 512] f16
  unsigned short* Bp = Ap + (size_t)n * KP;            // [m, 512] f16

  encode_kernel<<<dim3(M_SUB, n / 256), 256, 0, stream>>>(x, cen, Ap);
  decode_tgt<<<dim3((m * M_SUB) / 256), 256, 0, stream>>>(tgt, cen, Bp);
  gemm_nt<<<dim3(m / 128, n / 128), 256, 0, stream>>>(Ap, Bp, out, n, m);
}

// Round 3
// 147.471 us; speedup vs baseline: 2.3494x; 1.0947x over previous
//
#include <hip/hip_runtime.h>
#include <hip/hip_fp16.h>

// PQ sim: sim = decode(x) @ decode(tgt)^T via f16 GEMM (K=512).
// n=4096 queries, m=16384 targets, M=64 subspaces, ksub=256, dsub=8, D=512.
// GEMM: BM=256 BN=128 BK=64, 8 waves (4Mx2N), ring-of-3 LDS (144 KB),
// counted vmcnt(6) (T4), XOR slot swizzle (T2), setprio (T5), XCD swizzle (T1).

#define D_FULL 512
#define M_SUB 64
#define KSUB 256
#define DSUB 8
#define KP 512

typedef _Float16 f16x8 __attribute__((ext_vector_type(8)));
typedef float f32x4 __attribute__((ext_vector_type(4)));

static __device__ __forceinline__ unsigned int pack2h(float f0, float f1) {
  _Float16 h0 = (_Float16)f0, h1 = (_Float16)f1;
  unsigned short u0, u1;
  __builtin_memcpy(&u0, &h0, 2);
  __builtin_memcpy(&u1, &h1, 2);
  return (unsigned int)u0 | ((unsigned int)u1 << 16);
}

// ---------------- encode + decode queries into A' (f16) ----------------
__global__ void encode_kernel(const float* __restrict__ x,
                              const float* __restrict__ cen,
                              unsigned short* __restrict__ Ap) {
  __shared__ float cs[KSUB][DSUB];
  __shared__ float n2[KSUB];
  const int t = threadIdx.x;
  const int s = blockIdx.x;
  const int i = blockIdx.y * 256 + t;

  const float* cp = cen + ((size_t)s * KSUB + t) * DSUB;
  float4 c0 = *(const float4*)cp;
  float4 c1 = *(const float4*)(cp + 4);
  *(float4*)&cs[t][0] = c0;
  *(float4*)&cs[t][4] = c1;
  n2[t] = c0.x * c0.x + c0.y * c0.y + c0.z * c0.z + c0.w * c0.w +
          c1.x * c1.x + c1.y * c1.y + c1.z * c1.z + c1.w * c1.w;
  __syncthreads();

  float xq[8];
  const float* xp = x + (size_t)i * D_FULL + s * DSUB;
  *(float4*)&xq[0] = *(const float4*)xp;
  *(float4*)&xq[4] = *(const float4*)(xp + 4);

  float best = 1e30f;
  int bk = 0;
  for (int k = 0; k < KSUB; ++k) {
    float dot = 0.f;
#pragma unroll
    for (int d = 0; d < 8; ++d) dot += cs[k][d] * xq[d];
    float dis = n2[k] - 2.0f * dot;
    if (dis < best) { best = dis; bk = k; }  // strict < keeps first index (numpy argmin)
  }

  uint4 hv;
  hv.x = pack2h(cs[bk][0], cs[bk][1]);
  hv.y = pack2h(cs[bk][2], cs[bk][3]);
  hv.z = pack2h(cs[bk][4], cs[bk][5]);
  hv.w = pack2h(cs[bk][6], cs[bk][7]);
  *(uint4*)(Ap + (size_t)i * KP + s * DSUB) = hv;
}

// ---------------- decode targets into B' (f16) ----------------
__global__ void decode_tgt(const int* __restrict__ tgt,
                           const float* __restrict__ cen,
                           unsigned short* __restrict__ Bp) {
  int g = blockIdx.x * 256 + threadIdx.x;
  int j = g >> 6, s = g & 63;
  int k = tgt[g];
  const float* c = cen + ((size_t)s * KSUB + k) * DSUB;
  float4 v0 = *(const float4*)c;
  float4 v1 = *(const float4*)(c + 4);
  uint4 hv;
  hv.x = pack2h(v0.x, v0.y);
  hv.y = pack2h(v0.z, v0.w);
  hv.z = pack2h(v1.x, v1.y);
  hv.w = pack2h(v1.z, v1.w);
  *(uint4*)(Bp + (size_t)j * KP + s * DSUB) = hv;
}

// ---------------- GEMM: C[n,m] = A'[n,KP] * B'[m,KP]^T ----------------
// Stage tile T (BK=64 slice) into LDS slot. Per wave: 4 A-loads + 2 B-loads
// = 6 global_load_lds (vmcnt-tracked). LDS dest is linear (wave base+lane*16);
// swizzle applied on the GLOBAL source (rule #21) + matching read-side XOR.
#define STAGE(T, SLOT)                                                          \
  do {                                                                          \
    const int k0_ = (T) * 64;                                                   \
    unsigned short* as_ = &lds[(SLOT) * 24576];                                 \
    unsigned short* bs_ = as_ + 16384;                                          \
    _Pragma("unroll") for (int it = 0; it < 4; ++it) {                          \
      int R = w * 32 + it * 8;                                                  \
      int r = R + (l >> 3);                                                     \
      int c = (l & 7) ^ (r & 7);                                                \
      __builtin_amdgcn_global_load_lds(                                         \
          (const __attribute__((address_space(1))) void*)(Ab + (size_t)r * KP + \
                                                          k0_ + c * 8),         \
          (__attribute__((address_space(3))) void*)(as_ + R * 64 + l * 8), 16,  \
          0, 0);                                                                \
    }                                                                           \
    _Pragma("unroll") for (int it = 0; it < 2; ++it) {                          \
      int R = w * 16 + it * 8;                                                  \
      int r = R + (l >> 3);                                                     \
      int c = (l & 7) ^ (r & 7);                                                \
      __builtin_amdgcn_global_load_lds(                                         \
          (const __attribute__((address_space(1))) void*)(Bb + (size_t)r * KP + \
                                                          k0_ + c * 8),         \
          (__attribute__((address_space(3))) void*)(bs_ + R * 64 + l * 8), 16,  \
          0, 0);                                                                \
    }                                                                           \
  } while (0)

// Consume one K-tile from SLOT: 16 ds_read_b128 + 32 MFMA per wave.
#define COMPUTE(SLOT)                                                           \
  do {                                                                          \
    const unsigned short* as_ = &lds[(SLOT) * 24576];                           \
    const unsigned short* bs_ = as_ + 16384;                                    \
    _Pragma("unroll") for (int ks = 0; ks < 2; ++ks) {                          \
      f16x8 a_[4], b_[4];                                                       \
      int kq = ks * 4 + (l >> 4);                                               \
      _Pragma("unroll") for (int i2 = 0; i2 < 4; ++i2) {                        \
        int row = wm * 64 + i2 * 16 + (l & 15);                                 \
        a_[i2] = *(const f16x8*)&as_[row * 64 + ((kq ^ (row & 7)) * 8)];        \
      }                                                                         \
      _Pragma("unroll") for (int j2 = 0; j2 < 4; ++j2) {                        \
        int row = wn * 64 + j2 * 16 + (l & 15);                                 \
        b_[j2] = *(const f16x8*)&bs_[row * 64 + ((kq ^ (row & 7)) * 8)];        \
      }                                                                         \
      __builtin_amdgcn_s_setprio(1);                                            \
      _Pragma("unroll") for (int i2 = 0; i2 < 4; ++i2)                          \
          _Pragma("unroll") for (int j2 = 0; j2 < 4; ++j2) acc[i2][j2] =        \
          __builtin_amdgcn_mfma_f32_16x16x32_f16(a_[i2], b_[j2], acc[i2][j2],   \
                                                 0, 0, 0);                      \
      __builtin_amdgcn_s_setprio(0);                                            \
    }                                                                           \
  } while (0)

#define VMW(N) asm volatile("s_waitcnt vmcnt(" #N ")" ::: "memory")
#define BAR() __builtin_amdgcn_s_barrier()

__global__ __launch_bounds__(512, 2) void gemm_nt(
    const unsigned short* __restrict__ A, const unsigned short* __restrict__ B,
    float* __restrict__ C, int Nt) {
  __shared__ unsigned short lds[3 * 24576];  // 3 slots x (A 32KB + B 16KB) = 144 KB
  const int tid = threadIdx.x;
  const int w = tid >> 6, l = tid & 63;
  const int wm = w >> 1, wn = w & 1;

  // T1: XCD-aware bijective swizzle; nwg=2048, 2048%8==0.
  const int bid = blockIdx.x;
  const int swz = (bid & 7) * 256 + (bid >> 3);
  const int bm = swz >> 7;   // 0..15
  const int bn = swz & 127;  // 0..127

  const unsigned short* Ab = A + (size_t)bm * 256 * KP;
  const unsigned short* Bb = B + (size_t)bn * 128 * KP;

  f32x4 acc[4][4] = {};

  // Prologue: depth-2 prefetch. Outstanding 12; drain tile0 (oldest 6).
  STAGE(0, 0);
  STAGE(1, 1);
  VMW(6);
  BAR();

  // Steady state: stage t+2 into the slot freed at the previous boundary,
  // compute t, then drain tile t+1's 6 loads (leave t+2's 6 in flight).
  STAGE(2, 2); COMPUTE(0); VMW(6); BAR();  // t=0
  STAGE(3, 0); COMPUTE(1); VMW(6); BAR();  // t=1
  STAGE(4, 1); COMPUTE(2); VMW(6); BAR();  // t=2
  STAGE(5, 2); COMPUTE(0); VMW(6); BAR();  // t=3
  STAGE(6, 0); COMPUTE(1); VMW(6); BAR();  // t=4
  STAGE(7, 1); COMPUTE(2); VMW(6); BAR();  // t=5
  COMPUTE(0); VMW(0); BAR();               // t=6 (tail: drain tile 7)
  COMPUTE(1);                              // t=7

  // Epilogue: C/D layout col=lane&15, row=(lane>>4)*4+reg (verified m89/m91).
  const int rb = bm * 256 + wm * 64 + (l >> 4) * 4;
  const int cb = bn * 128 + wn * 64 + (l & 15);
#pragma unroll
  for (int i2 = 0; i2 < 4; ++i2)
#pragma unroll
    for (int j2 = 0; j2 < 4; ++j2)
#pragma unroll
      for (int r = 0; r < 4; ++r)
        C[(size_t)(rb + i2 * 16 + r) * Nt + cb + j2 * 16] = acc[i2][j2][r];
}

extern "C" void kernel_launch(void* const* d_in, const int* in_sizes, int n_in,
                              void* d_out, int out_size, void* d_ws, size_t ws_size,
                              hipStream_t stream) {
  const float* x = (const float*)d_in[0];    // [n, 512]
  const float* cen = (const float*)d_in[1];  // [64, 256, 8]
  const int* tgt = (const int*)d_in[2];      // [m, 64]
  float* out = (float*)d_out;                // [n, m]
  const int n = in_sizes[0] / D_FULL;        // 4096
  const int m = in_sizes[2] / M_SUB;         // 16384

  unsigned short* Ap = (unsigned short*)d_ws;  // [n, 512] f16
  unsigned short* Bp = Ap + (size_t)n * KP;    // [m, 512] f16

  encode_kernel<<<dim3(M_SUB, n / 256), 256, 0, stream>>>(x, cen, Ap);
  decode_tgt<<<dim3((m * M_SUB) / 256), 256, 0, stream>>>(tgt, cen, Bp);
  gemm_nt<<<dim3((n / 256) * (m / 128)), 512, 0, stream>>>(Ap, Bp, out, m);
}